// Round 21
// baseline (204.220 us; speedup 1.0000x reference)
//
#include <hip/hip_runtime.h>
#include <hip/hip_bf16.h>

#define S_LEN 4096
#define DMODEL 1024
#define NHEAD 16
#define DK 64

typedef __hip_bfloat16 bf16;
typedef __attribute__((ext_vector_type(8))) __bf16 bf16x8;
typedef __attribute__((ext_vector_type(4))) float f32x4;

__device__ __forceinline__ f32x4 mfma16(bf16x8 a, bf16x8 b, f32x4 c) {
    return __builtin_amdgcn_mfma_f32_16x16x32_bf16(a, b, c, 0, 0, 0);
}

// async global->LDS, 16B per lane. LDS dest is wave-uniform base + lane*16.
__device__ __forceinline__ void async16(const bf16* g, bf16* l) {
    __builtin_amdgcn_global_load_lds(
        (const __attribute__((address_space(1))) unsigned int*)g,
        (__attribute__((address_space(3))) unsigned int*)l, 16, 0, 0);
}

__device__ __forceinline__ bf16x8 cvt8(float4 a, float4 b) {
    bf16x8 r;
    r[0] = (__bf16)a.x; r[1] = (__bf16)a.y; r[2] = (__bf16)a.z; r[3] = (__bf16)a.w;
    r[4] = (__bf16)b.x; r[5] = (__bf16)b.y; r[6] = (__bf16)b.z; r[7] = (__bf16)b.w;
    return r;
}

// pack two f32 -> u32 of 2 bf16 (RNE)
__device__ __forceinline__ unsigned int pkbf(float lo, float hi) {
    unsigned short a = __bfloat16_as_ushort(__float2bfloat16(lo));
    unsigned short b = __bfloat16_as_ushort(__float2bfloat16(hi));
    return (unsigned int)a | ((unsigned int)b << 16);
}

// XOR-swizzled index into a [rows][64] bf16 tile (128B rows): 16B slot ^ (row&7).
__device__ __forceinline__ int swz8(int row, int col8) {  // col8 = col>>3
    return row * 64 + ((col8 ^ (row & 7)) << 3);
}

// K-row placement permutation: position p holds original kv with
// p = [b5 b2 b4 b3 b1 b0]. Makes swapped-QK^T leave each q-row's P values
// lane-local in PV A-frag order (kv = lhi*8 + j) -> zero-shuffle PV.
__device__ __forceinline__ int kperm(int kv) {
    return (kv & 0x23) | ((kv & 0x04) << 2) | ((kv & 0x18) >> 1);
}

// XCD-aware remap (T1): 256 linear blocks -> (ybm in 0..31, xbn in 0..7) such
// that the 8 blocks sharing ybm have identical lin%8 -> land on one XCD under
// round-robin dispatch -> the shared 2MB A-row-panel stays L2-resident.
__device__ __forceinline__ void xcd_remap(int lin, int& ybm, int& xbn) {
    const int q = lin >> 3, r = lin & 7;
    ybm = r * 4 + (q >> 3);
    xbn = q & 7;
}

// C[M][N] = A[M][K=1024] * B[N][K]^T, 128x128 tile, bf16 MFMA compute.
// MODE 0 (Q/K proj): A = f32 x, out = bf16 head-major [h][s][dk], scale folded
// MODE 1 (OUT proj): A = bf16 ws (global_load_lds), out = f32 row-major C[m][n]
// MODE 2 (V^T proj): A = f32 Wv, B = f32 x, out = bf16 [h=m>>6][d=m&63][s=n]
template <int MODE>
__device__ __forceinline__ void gemm_body(const void* Ap, const float* B,
                                          void* Cp, float scale, int bm, int bn) {
    constexpr int K = DMODEL;
    __shared__ bf16 As[128 * 32];
    __shared__ bf16 Bs[128 * 32];

    const int t = threadIdx.x;
    const int lane = t & 63;
    const int l15 = lane & 15, lhi = lane >> 4;
    const int wave = t >> 6;
    const int wm = wave >> 1, wn = wave & 1;

    const int srow = t >> 2, scol = (t & 3) * 8;

    const float* gB = B + (size_t)(bn * 128 + srow) * K + scol;
    const float* gAf = (const float*)Ap + (size_t)(bm * 128 + srow) * K + scol;
    const bf16* gAb = (const bf16*)Ap + (size_t)(bm * 128 + srow) * K + scol;

    f32x4 acc[4][4];
#pragma unroll
    for (int i = 0; i < 4; ++i)
#pragma unroll
        for (int j = 0; j < 4; ++j) acc[i][j] = (f32x4){0.f, 0.f, 0.f, 0.f};

    for (int kt = 0; kt < K / 32; ++kt) {
        if (MODE != 1) {
            float4 a0 = *(const float4*)(gAf + kt * 32);
            float4 a1 = *(const float4*)(gAf + kt * 32 + 4);
            *(bf16x8*)&As[srow * 32 + scol] = cvt8(a0, a1);
            float4 a2 = *(const float4*)(gAf + kt * 32 + 64 * K);
            float4 a3 = *(const float4*)(gAf + kt * 32 + 64 * K + 4);
            *(bf16x8*)&As[2048 + srow * 32 + scol] = cvt8(a2, a3);
        } else {
            async16(gAb + kt * 32,          (bf16*)As + t * 8);
            async16(gAb + kt * 32 + 64 * K, (bf16*)As + 2048 + t * 8);
        }
        {
            float4 b0 = *(const float4*)(gB + kt * 32);
            float4 b1 = *(const float4*)(gB + kt * 32 + 4);
            *(bf16x8*)&Bs[srow * 32 + scol] = cvt8(b0, b1);
            float4 b2 = *(const float4*)(gB + kt * 32 + 64 * K);
            float4 b3 = *(const float4*)(gB + kt * 32 + 64 * K + 4);
            *(bf16x8*)&Bs[2048 + srow * 32 + scol] = cvt8(b2, b3);
        }
        __syncthreads();

        bf16x8 af[4], bv[4];
#pragma unroll
        for (int mt = 0; mt < 4; ++mt)
            af[mt] = *(const bf16x8*)&As[(wm * 64 + mt * 16 + l15) * 32 + lhi * 8];
#pragma unroll
        for (int nt = 0; nt < 4; ++nt)
            bv[nt] = *(const bf16x8*)&Bs[(wn * 64 + nt * 16 + l15) * 32 + lhi * 8];
#pragma unroll
        for (int mt = 0; mt < 4; ++mt)
#pragma unroll
            for (int nt = 0; nt < 4; ++nt)
                acc[mt][nt] = mfma16(af[mt], bv[nt], acc[mt][nt]);
        __syncthreads();
    }

#pragma unroll
    for (int mt = 0; mt < 4; ++mt)
#pragma unroll
        for (int nt = 0; nt < 4; ++nt)
#pragma unroll
            for (int r = 0; r < 4; ++r) {
                int m = bm * 128 + wm * 64 + mt * 16 + lhi * 4 + r;
                int n = bn * 128 + wn * 64 + nt * 16 + l15;
                float v = acc[mt][nt][r] * scale;
                if (MODE == 0)
                    ((bf16*)Cp)[((size_t)(n >> 6) * S_LEN + m) * DK + (n & 63)] =
                        __float2bfloat16(v);
                else if (MODE == 1)
                    ((float*)Cp)[(size_t)m * DMODEL + n] = v;
                else  // MODE 2: [h][d][s]
                    ((bf16*)Cp)[((size_t)(m >> 6) * DK + (m & 63)) * S_LEN + n] =
                        __float2bfloat16(v);
            }
}

// One launch, grid (256, 1, 3): z=0 Q, z=1 K (MODE 0), z=2 V^T (MODE 2).
__global__ __launch_bounds__(256) void qkv_proj(const float* __restrict__ x,
                                                const float* __restrict__ Wq,
                                                const float* __restrict__ Wk,
                                                const float* __restrict__ Wv,
                                                bf16* __restrict__ q,
                                                bf16* __restrict__ k,
                                                bf16* __restrict__ vT) {
    int ybm, xbn;
    xcd_remap(blockIdx.x, ybm, xbn);
    const int z = blockIdx.z;
    if (z == 2) {
        gemm_body<2>(Wv, x, vT, 1.0f, xbn, ybm);
    } else {
        const float* B = (z == 0) ? Wq : Wk;
        bf16* out = (z == 0) ? q : k;
        float scale = (z == 0) ? 0.18033688011112042f : 1.0f;  // (1/sqrt64)*log2e
        gemm_body<0>(x, B, out, scale, ybm, xbn);
    }
}

__global__ __launch_bounds__(256) void out_proj(const bf16* __restrict__ A,
                                                const float* __restrict__ Wo,
                                                float* __restrict__ C) {
    int ybm, xbn;
    xcd_remap(blockIdx.x, ybm, xbn);
    gemm_body<1>(A, Wo, C, 1.0f, ybm, xbn);
}

// Flash attention, causal. TWO q-row groups per wave (T15-style dual pipeline):
// block covers a 128-row q-tile; wave w owns qA = tile + w*16 (rows 0..63) and
// qB = tile + 64 + w*16 (rows 64..127). The two groups' chains are independent
// -> scheduler overlaps B's MFMAs with A's softmax stalls, and every kf/vf LDS
// fragment read serves BOTH groups (LDS-read per q-row halves). KVBLK=128
// staging (one barrier pair per 128 kv), sequential 64-kv subtiles, R12-proven
// per-group inner body. Grid 512; classes {c, c+256} sum to exactly 34 steps.
// Spill discipline: separate straight-line bodies for both-active vs B-only
// (actA implies actB), named arrays, static indices, s scoped per body.
__global__ __launch_bounds__(256) void attn_kernel(const bf16* __restrict__ Q,
                                                   const bf16* __restrict__ Kg,
                                                   const bf16* __restrict__ Vtg,
                                                   bf16* __restrict__ O) {
    __shared__ bf16 Ks[2][64 * 64];   // [kv-subtile][swizzled kperm'd rows]
    __shared__ bf16 Vt[2][64 * 64];   // [kv-subtile][swizzled [d][kv64]]

    const int b = blockIdx.x;
    const int t = threadIdx.x;
    const int lane = t & 63;
    const int l15 = lane & 15, lhi = lane >> 4;
    const int wave = t >> 6;

    // K staging: 128 rows x 2 threads/row, 4 x 16B slots each
    const int srowK = t >> 1, halfK = t & 1;
    const int subK = srowK >> 6;
    const int kposK = kperm(srowK & 63);
    // V staging: 64 d-rows x 4 threads/row, 4 x 16B slots (qv pair -> subtile)
    const int srowV = t >> 2, qv = t & 3;
    const int vsub = qv >> 1, vcol = (qv & 1) * 4;

    // balanced mapping over 512 units of 128-row q-tiles: {c, c+256} -> 34 steps
    const int g = b >> 8, idx = b & 255;
    const int j = idx >> 4, h = idx & 15;
    const int qt = (g == 0) ? (31 - j) : j;

    const bf16* qh = Q + (size_t)h * S_LEN * DK;
    const bf16* kh = Kg + (size_t)h * S_LEN * DK;
    const bf16* vh = Vtg + (size_t)h * DK * S_LEN;  // [d][s]

    const int qA = qt * 128 + wave * 16;        // group A: tile rows 0..63
    const int qB = qt * 128 + 64 + wave * 16;   // group B: tile rows 64..127

    // Q B-fragments per group (scale+log2e folded in Q)
    bf16x8 qfA0 = *(const bf16x8*)&qh[(size_t)(qA + l15) * DK + lhi * 8];
    bf16x8 qfA1 = *(const bf16x8*)&qh[(size_t)(qA + l15) * DK + 32 + lhi * 8];
    bf16x8 qfB0 = *(const bf16x8*)&qh[(size_t)(qB + l15) * DK + lhi * 8];
    bf16x8 qfB1 = *(const bf16x8*)&qh[(size_t)(qB + l15) * DK + 32 + lhi * 8];

    float mA = -3.0e38f, lA = 0.f, mB = -3.0e38f, lB = 0.f;
    f32x4 oA[4], oB[4];
#pragma unroll
    for (int d = 0; d < 4; ++d) {
        oA[d] = (f32x4){0.f, 0.f, 0.f, 0.f};
        oB[d] = (f32x4){0.f, 0.f, 0.f, 0.f};
    }

    const int NT2 = qt + 1;  // 128-wide staging steps (kv up to 128*(qt+1))
    uint4 kr0, kr1, kr2, kr3, vr0, vr1, vr2, vr3;

    auto load_regs = [&](int kt) {
        const int k0 = kt * 128;
        const bf16* kp = &kh[(size_t)(k0 + srowK) * DK + halfK * 32];
        kr0 = *(const uint4*)(kp);
        kr1 = *(const uint4*)(kp + 8);
        kr2 = *(const uint4*)(kp + 16);
        kr3 = *(const uint4*)(kp + 24);
        const bf16* vp = &vh[(size_t)srowV * S_LEN + k0 + qv * 32];
        vr0 = *(const uint4*)(vp);
        vr1 = *(const uint4*)(vp + 8);
        vr2 = *(const uint4*)(vp + 16);
        vr3 = *(const uint4*)(vp + 24);
    };
    auto write_lds = [&]() {
        *(uint4*)&Ks[subK][swz8(kposK, halfK * 4 + 0)] = kr0;
        *(uint4*)&Ks[subK][swz8(kposK, halfK * 4 + 1)] = kr1;
        *(uint4*)&Ks[subK][swz8(kposK, halfK * 4 + 2)] = kr2;
        *(uint4*)&Ks[subK][swz8(kposK, halfK * 4 + 3)] = kr3;
        *(uint4*)&Vt[vsub][swz8(srowV, vcol + 0)] = vr0;
        *(uint4*)&Vt[vsub][swz8(srowV, vcol + 1)] = vr1;
        *(uint4*)&Vt[vsub][swz8(srowV, vcol + 2)] = vr2;
        *(uint4*)&Vt[vsub][swz8(srowV, vcol + 3)] = vr3;
    };

    load_regs(0);
    write_lds();
    __syncthreads();

    for (int kt = 0; kt < NT2; ++kt) {
        if (kt + 1 < NT2) load_regs(kt + 1);

#pragma unroll
        for (int sub = 0; sub < 2; ++sub) {
            const int k0 = kt * 128 + sub * 64;
            const bool actA = (k0 <= qA + 15);
            const bool actB = (k0 <= qB + 15);  // actA implies actB

            if (actA) {
                // ================= BOTH GROUPS (dual pipeline) =================
                f32x4 sA[4], sB[4];
                __builtin_amdgcn_s_setprio(1);
#pragma unroll
                for (int nt = 0; nt < 4; ++nt) {
                    bf16x8 kf0 = *(const bf16x8*)&Ks[sub][swz8(nt * 16 + l15, lhi)];
                    bf16x8 kf1 =
                        *(const bf16x8*)&Ks[sub][swz8(nt * 16 + l15, 4 + lhi)];
                    f32x4 cA = (f32x4){0.f, 0.f, 0.f, 0.f};
                    cA = mfma16(kf0, qfA0, cA);
                    cA = mfma16(kf1, qfA1, cA);
                    sA[nt] = cA;
                    f32x4 cB = (f32x4){0.f, 0.f, 0.f, 0.f};
                    cB = mfma16(kf0, qfB0, cB);
                    cB = mfma16(kf1, qfB1, cB);
                    sB[nt] = cB;
                }
                __builtin_amdgcn_s_setprio(0);

                if (k0 + 63 > qA) {
                    const int qg = qA + l15;
#pragma unroll
                    for (int nt = 0; nt < 4; ++nt)
#pragma unroll
                        for (int r = 0; r < 4; ++r) {
                            int kg = k0 + (nt >> 1) * 32 + lhi * 8 +
                                     (nt & 1) * 4 + r;
                            if (kg > qg) sA[nt][r] = -3.0e38f;
                        }
                }
                // B mask: k0+63 > qB only possible on the tile diagonal
                if (k0 + 63 > qB) {
                    const int qg = qB + l15;
#pragma unroll
                    for (int nt = 0; nt < 4; ++nt)
#pragma unroll
                        for (int r = 0; r < 4; ++r) {
                            int kg = k0 + (nt >> 1) * 32 + lhi * 8 +
                                     (nt & 1) * 4 + r;
                            if (kg > qg) sB[nt][r] = -3.0e38f;
                        }
                }

                // ---- softmax A ----
                {
                    float tm = sA[0][0];
#pragma unroll
                    for (int nt = 0; nt < 4; ++nt)
#pragma unroll
                        for (int r = 0; r < 4; ++r) tm = fmaxf(tm, sA[nt][r]);
                    tm = fmaxf(tm, __shfl_xor(tm, 16));
                    tm = fmaxf(tm, __shfl_xor(tm, 32));
                    if (__any(tm - mA > 8.0f)) {
                        float mn = fmaxf(mA, tm);
                        float alpha = exp2f(mA - mn);
                        mA = mn;
                        lA *= alpha;
                        float aR[4];
#pragma unroll
                        for (int r = 0; r < 4; ++r)
                            aR[r] = __shfl(alpha, (lane & 48) | (lhi * 4 + r));
#pragma unroll
                        for (int dt = 0; dt < 4; ++dt)
#pragma unroll
                            for (int r = 0; r < 4; ++r) oA[dt][r] *= aR[r];
                    }
                    float rs = 0.f;
#pragma unroll
                    for (int nt = 0; nt < 4; ++nt)
#pragma unroll
                        for (int r = 0; r < 4; ++r) {
                            float pv = exp2f(sA[nt][r] - mA);
                            sA[nt][r] = pv;
                            rs += pv;
                        }
                    rs += __shfl_xor(rs, 16);
                    rs += __shfl_xor(rs, 32);
                    lA += rs;
                }
                // ---- softmax B (independent chain) ----
                {
                    float tm = sB[0][0];
#pragma unroll
                    for (int nt = 0; nt < 4; ++nt)
#pragma unroll
                        for (int r = 0; r < 4; ++r) tm = fmaxf(tm, sB[nt][r]);
                    tm = fmaxf(tm, __shfl_xor(tm, 16));
                    tm = fmaxf(tm, __shfl_xor(tm, 32));
                    if (__any(tm - mB > 8.0f)) {
                        float mn = fmaxf(mB, tm);
                        float alpha = exp2f(mB - mn);
                        mB = mn;
                        lB *= alpha;
                        float aR[4];
#pragma unroll
                        for (int r = 0; r < 4; ++r)
                            aR[r] = __shfl(alpha, (lane & 48) | (lhi * 4 + r));
#pragma unroll
                        for (int dt = 0; dt < 4; ++dt)
#pragma unroll
                            for (int r = 0; r < 4; ++r) oB[dt][r] *= aR[r];
                    }
                    float rs = 0.f;
#pragma unroll
                    for (int nt = 0; nt < 4; ++nt)
#pragma unroll
                        for (int r = 0; r < 4; ++r) {
                            float pv = exp2f(sB[nt][r] - mB);
                            sB[nt][r] = pv;
                            rs += pv;
                        }
                    rs += __shfl_xor(rs, 16);
                    rs += __shfl_xor(rs, 32);
                    lB += rs;
                }

                // ---- PV: shared vf serves both groups ----
#pragma unroll
                for (int kc = 0; kc < 2; ++kc) {
                    union { unsigned int u[4]; bf16x8 v; } pfA, pfB;
                    pfA.u[0] = pkbf(sA[2 * kc][0], sA[2 * kc][1]);
                    pfA.u[1] = pkbf(sA[2 * kc][2], sA[2 * kc][3]);
                    pfA.u[2] = pkbf(sA[2 * kc + 1][0], sA[2 * kc + 1][1]);
                    pfA.u[3] = pkbf(sA[2 * kc + 1][2], sA[2 * kc + 1][3]);
                    pfB.u[0] = pkbf(sB[2 * kc][0], sB[2 * kc][1]);
                    pfB.u[1] = pkbf(sB[2 * kc][2], sB[2 * kc][3]);
                    pfB.u[2] = pkbf(sB[2 * kc + 1][0], sB[2 * kc + 1][1]);
                    pfB.u[3] = pkbf(sB[2 * kc + 1][2], sB[2 * kc + 1][3]);
                    __builtin_amdgcn_s_setprio(1);
#pragma unroll
                    for (int dt = 0; dt < 4; ++dt) {
                        bf16x8 vf = *(const bf16x8*)
                            &Vt[sub][swz8(dt * 16 + l15, kc * 4 + lhi)];
                        oA[dt] = mfma16(pfA.v, vf, oA[dt]);
                        oB[dt] = mfma16(pfB.v, vf, oB[dt]);
                    }
                    __builtin_amdgcn_s_setprio(0);
                }
            } else if (actB) {
                // ================= GROUP B ONLY =================
                f32x4 sB[4];
                __builtin_amdgcn_s_setprio(1);
#pragma unroll
                for (int nt = 0; nt < 4; ++nt) {
                    bf16x8 kf0 = *(const bf16x8*)&Ks[sub][swz8(nt * 16 + l15, lhi)];
                    bf16x8 kf1 =
                        *(const bf16x8*)&Ks[sub][swz8(nt * 16 + l15, 4 + lhi)];
                    f32x4 cB = (f32x4){0.f, 0.f, 0.f, 0.f};
                    cB = mfma16(kf0, qfB0, cB);
                    cB = mfma16(kf1, qfB1, cB);
                    sB[nt] = cB;
                }
                __builtin_amdgcn_s_setprio(0);

                if (k0 + 63 > qB) {
                    const int qg = qB + l15;
#pragma unroll
                    for (int nt = 0; nt < 4; ++nt)
#pragma unroll
                        for (int r = 0; r < 4; ++r) {
                            int kg = k0 + (nt >> 1) * 32 + lhi * 8 +
                                     (nt & 1) * 4 + r;
                            if (kg > qg) sB[nt][r] = -3.0e38f;
                        }
                }

                float tm = sB[0][0];
#pragma unroll
                for (int nt = 0; nt < 4; ++nt)
#pragma unroll
                    for (int r = 0; r < 4; ++r) tm = fmaxf(tm, sB[nt][r]);
                tm = fmaxf(tm, __shfl_xor(tm, 16));
                tm = fmaxf(tm, __shfl_xor(tm, 32));
                if (__any(tm - mB > 8.0f)) {
                    float mn = fmaxf(mB, tm);
                    float alpha = exp2f(mB - mn);
                    mB = mn;
                    lB *= alpha;
                    float aR[4];
#pragma unroll
                    for (int r = 0; r < 4; ++r)
                        aR[r] = __shfl(alpha, (lane & 48) | (lhi * 4 + r));
#pragma unroll
                    for (int dt = 0; dt < 4; ++dt)
#pragma unroll
                        for (int r = 0; r < 4; ++r) oB[dt][r] *= aR[r];
                }
                float rs = 0.f;
#pragma unroll
                for (int nt = 0; nt < 4; ++nt)
#pragma unroll
                    for (int r = 0; r < 4; ++r) {
                        float pv = exp2f(sB[nt][r] - mB);
                        sB[nt][r] = pv;
                        rs += pv;
                    }
                rs += __shfl_xor(rs, 16);
                rs += __shfl_xor(rs, 32);
                lB += rs;

#pragma unroll
                for (int kc = 0; kc < 2; ++kc) {
                    union { unsigned int u[4]; bf16x8 v; } pfB;
                    pfB.u[0] = pkbf(sB[2 * kc][0], sB[2 * kc][1]);
                    pfB.u[1] = pkbf(sB[2 * kc][2], sB[2 * kc][3]);
                    pfB.u[2] = pkbf(sB[2 * kc + 1][0], sB[2 * kc + 1][1]);
                    pfB.u[3] = pkbf(sB[2 * kc + 1][2], sB[2 * kc + 1][3]);
                    __builtin_amdgcn_s_setprio(1);
#pragma unroll
                    for (int dt = 0; dt < 4; ++dt) {
                        bf16x8 vf = *(const bf16x8*)
                            &Vt[sub][swz8(dt * 16 + l15, kc * 4 + lhi)];
                        oB[dt] = mfma16(pfB.v, vf, oB[dt]);
                    }
                    __builtin_amdgcn_s_setprio(0);
                }
            }
        }

        __syncthreads();  // all LDS reads of this 128-tile done
        if (kt + 1 < NT2) {
            write_lds();
            __syncthreads();  // writes visible before next compute
        }
    }

    // ---- output: both groups ----
    {
        float lR[4];
#pragma unroll
        for (int r = 0; r < 4; ++r)
            lR[r] = __shfl(lA, (lane & 48) | (lhi * 4 + r));
#pragma unroll
        for (int dt = 0; dt < 4; ++dt)
#pragma unroll
            for (int r = 0; r < 4; ++r) {
                int qg = qA + lhi * 4 + r;
                int dg = dt * 16 + l15;
                O[(size_t)qg * DMODEL + h * DK + dg] =
                    __float2bfloat16(oA[dt][r] / lR[r]);
            }
    }
    {
        float lR[4];
#pragma unroll
        for (int r = 0; r < 4; ++r)
            lR[r] = __shfl(lB, (lane & 48) | (lhi * 4 + r));
#pragma unroll
        for (int dt = 0; dt < 4; ++dt)
#pragma unroll
            for (int r = 0; r < 4; ++r) {
                int qg = qB + lhi * 4 + r;
                int dg = dt * 16 + l15;
                O[(size_t)qg * DMODEL + h * DK + dg] =
                    __float2bfloat16(oB[dt][r] / lR[r]);
            }
    }
}

extern "C" void kernel_launch(void* const* d_in, const int* in_sizes, int n_in,
                              void* d_out, int out_size, void* d_ws, size_t ws_size,
                              hipStream_t stream) {
    const float* x  = (const float*)d_in[0];
    const float* Wq = (const float*)d_in[1];
    const float* Wk = (const float*)d_in[2];
    const float* Wv = (const float*)d_in[3];
    const float* Wo = (const float*)d_in[4];
    float* out = (float*)d_out;

    bf16* q_ws = (bf16*)d_ws;                    // [H][S][64] bf16
    bf16* k_ws = q_ws + (size_t)S_LEN * DMODEL;  // [H][S][64] bf16
    bf16* v_ws = k_ws + (size_t)S_LEN * DMODEL;  // [H][64][S] bf16 (V^T)
    bf16* a_ws = v_ws + (size_t)S_LEN * DMODEL;  // [S][D] bf16

    dim3 gq(256, 1, 3);
    qkv_proj<<<gq, 256, 0, stream>>>(x, Wq, Wk, Wv, q_ws, k_ws, v_ws);
    attn_kernel<<<512, 256, 0, stream>>>(q_ws, k_ws, v_ws, a_ws);
    out_proj<<<256, 256, 0, stream>>>(a_ws, Wo, out);
}

// Round 22
// 171.222 us; speedup vs baseline: 1.1927x; 1.1927x over previous
//
#include <hip/hip_runtime.h>
#include <hip/hip_bf16.h>

#define S_LEN 4096
#define DMODEL 1024
#define NHEAD 16
#define DK 64

typedef __hip_bfloat16 bf16;
typedef __attribute__((ext_vector_type(8))) __bf16 bf16x8;
typedef __attribute__((ext_vector_type(4))) float f32x4;

__device__ __forceinline__ f32x4 mfma16(bf16x8 a, bf16x8 b, f32x4 c) {
    return __builtin_amdgcn_mfma_f32_16x16x32_bf16(a, b, c, 0, 0, 0);
}

// async global->LDS, 16B per lane. LDS dest is wave-uniform base + lane*16.
__device__ __forceinline__ void async16(const bf16* g, bf16* l) {
    __builtin_amdgcn_global_load_lds(
        (const __attribute__((address_space(1))) unsigned int*)g,
        (__attribute__((address_space(3))) unsigned int*)l, 16, 0, 0);
}

__device__ __forceinline__ bf16x8 cvt8(float4 a, float4 b) {
    bf16x8 r;
    r[0] = (__bf16)a.x; r[1] = (__bf16)a.y; r[2] = (__bf16)a.z; r[3] = (__bf16)a.w;
    r[4] = (__bf16)b.x; r[5] = (__bf16)b.y; r[6] = (__bf16)b.z; r[7] = (__bf16)b.w;
    return r;
}

// pack two f32 -> u32 of 2 bf16 (RNE)
__device__ __forceinline__ unsigned int pkbf(float lo, float hi) {
    unsigned short a = __bfloat16_as_ushort(__float2bfloat16(lo));
    unsigned short b = __bfloat16_as_ushort(__float2bfloat16(hi));
    return (unsigned int)a | ((unsigned int)b << 16);
}

// XOR-swizzled index into a [rows][64] bf16 tile (128B rows): 16B slot ^ (row&7).
__device__ __forceinline__ int swz8(int row, int col8) {  // col8 = col>>3
    return row * 64 + ((col8 ^ (row & 7)) << 3);
}

// K-row placement permutation: position p holds original kv with
// p = [b5 b2 b4 b3 b1 b0]. Makes swapped-QK^T leave each q-row's P values
// lane-local in PV A-frag order (kv = lhi*8 + j) -> zero-shuffle PV.
__device__ __forceinline__ int kperm(int kv) {
    return (kv & 0x23) | ((kv & 0x04) << 2) | ((kv & 0x18) >> 1);
}

// XCD-aware remap (T1): 256 linear blocks -> (ybm in 0..31, xbn in 0..7) such
// that the 8 blocks sharing ybm have identical lin%8 -> land on one XCD under
// round-robin dispatch -> the shared 2MB A-row-panel stays L2-resident.
__device__ __forceinline__ void xcd_remap(int lin, int& ybm, int& xbn) {
    const int q = lin >> 3, r = lin & 7;
    ybm = r * 4 + (q >> 3);
    xbn = q & 7;
}

// C[M][N] = A[M][K=1024] * B[N][K]^T, 128x128 tile, bf16 MFMA compute.
// MODE 0 (Q/K proj): A = f32 x, out = bf16 head-major [h][s][dk], scale folded
// MODE 1 (OUT proj): A = bf16 ws (global_load_lds), out = f32 row-major C[m][n]
// MODE 2 (V^T proj): A = f32 Wv, B = f32 x, out = bf16 [h=m>>6][d=m&63][s=n]
template <int MODE>
__device__ __forceinline__ void gemm_body(const void* Ap, const float* B,
                                          void* Cp, float scale, int bm, int bn) {
    constexpr int K = DMODEL;
    __shared__ bf16 As[128 * 32];
    __shared__ bf16 Bs[128 * 32];

    const int t = threadIdx.x;
    const int lane = t & 63;
    const int l15 = lane & 15, lhi = lane >> 4;
    const int wave = t >> 6;
    const int wm = wave >> 1, wn = wave & 1;

    const int srow = t >> 2, scol = (t & 3) * 8;

    const float* gB = B + (size_t)(bn * 128 + srow) * K + scol;
    const float* gAf = (const float*)Ap + (size_t)(bm * 128 + srow) * K + scol;
    const bf16* gAb = (const bf16*)Ap + (size_t)(bm * 128 + srow) * K + scol;

    f32x4 acc[4][4];
#pragma unroll
    for (int i = 0; i < 4; ++i)
#pragma unroll
        for (int j = 0; j < 4; ++j) acc[i][j] = (f32x4){0.f, 0.f, 0.f, 0.f};

    for (int kt = 0; kt < K / 32; ++kt) {
        if (MODE != 1) {
            float4 a0 = *(const float4*)(gAf + kt * 32);
            float4 a1 = *(const float4*)(gAf + kt * 32 + 4);
            *(bf16x8*)&As[srow * 32 + scol] = cvt8(a0, a1);
            float4 a2 = *(const float4*)(gAf + kt * 32 + 64 * K);
            float4 a3 = *(const float4*)(gAf + kt * 32 + 64 * K + 4);
            *(bf16x8*)&As[2048 + srow * 32 + scol] = cvt8(a2, a3);
        } else {
            async16(gAb + kt * 32,          (bf16*)As + t * 8);
            async16(gAb + kt * 32 + 64 * K, (bf16*)As + 2048 + t * 8);
        }
        {
            float4 b0 = *(const float4*)(gB + kt * 32);
            float4 b1 = *(const float4*)(gB + kt * 32 + 4);
            *(bf16x8*)&Bs[srow * 32 + scol] = cvt8(b0, b1);
            float4 b2 = *(const float4*)(gB + kt * 32 + 64 * K);
            float4 b3 = *(const float4*)(gB + kt * 32 + 64 * K + 4);
            *(bf16x8*)&Bs[2048 + srow * 32 + scol] = cvt8(b2, b3);
        }
        __syncthreads();

        bf16x8 af[4], bv[4];
#pragma unroll
        for (int mt = 0; mt < 4; ++mt)
            af[mt] = *(const bf16x8*)&As[(wm * 64 + mt * 16 + l15) * 32 + lhi * 8];
#pragma unroll
        for (int nt = 0; nt < 4; ++nt)
            bv[nt] = *(const bf16x8*)&Bs[(wn * 64 + nt * 16 + l15) * 32 + lhi * 8];
#pragma unroll
        for (int mt = 0; mt < 4; ++mt)
#pragma unroll
            for (int nt = 0; nt < 4; ++nt)
                acc[mt][nt] = mfma16(af[mt], bv[nt], acc[mt][nt]);
        __syncthreads();
    }

#pragma unroll
    for (int mt = 0; mt < 4; ++mt)
#pragma unroll
        for (int nt = 0; nt < 4; ++nt)
#pragma unroll
            for (int r = 0; r < 4; ++r) {
                int m = bm * 128 + wm * 64 + mt * 16 + lhi * 4 + r;
                int n = bn * 128 + wn * 64 + nt * 16 + l15;
                float v = acc[mt][nt][r] * scale;
                if (MODE == 0)
                    ((bf16*)Cp)[((size_t)(n >> 6) * S_LEN + m) * DK + (n & 63)] =
                        __float2bfloat16(v);
                else if (MODE == 1)
                    ((float*)Cp)[(size_t)m * DMODEL + n] = v;
                else  // MODE 2: [h][d][s]
                    ((bf16*)Cp)[((size_t)(m >> 6) * DK + (m & 63)) * S_LEN + n] =
                        __float2bfloat16(v);
            }
}

// One launch, grid (256, 1, 3): z=0 Q, z=1 K (MODE 0), z=2 V^T (MODE 2).
__global__ __launch_bounds__(256) void qkv_proj(const float* __restrict__ x,
                                                const float* __restrict__ Wq,
                                                const float* __restrict__ Wk,
                                                const float* __restrict__ Wv,
                                                bf16* __restrict__ q,
                                                bf16* __restrict__ k,
                                                bf16* __restrict__ vT) {
    int ybm, xbn;
    xcd_remap(blockIdx.x, ybm, xbn);
    const int z = blockIdx.z;
    if (z == 2) {
        gemm_body<2>(Wv, x, vT, 1.0f, xbn, ybm);
    } else {
        const float* B = (z == 0) ? Wq : Wk;
        bf16* out = (z == 0) ? q : k;
        float scale = (z == 0) ? 0.18033688011112042f : 1.0f;  // (1/sqrt64)*log2e
        gemm_body<0>(x, B, out, scale, ybm, xbn);
    }
}

__global__ __launch_bounds__(256) void out_proj(const bf16* __restrict__ A,
                                                const float* __restrict__ Wo,
                                                float* __restrict__ C) {
    int ybm, xbn;
    xcd_remap(blockIdx.x, ybm, xbn);
    gemm_body<1>(A, Wo, C, 1.0f, ybm, xbn);
}

// Flash attention, causal. KVBLK=128 STAGING with SEQUENTIAL 64-kv subtile
// compute (best measured: 171.3us total, attn ~105us): both subtiles staged
// in one burst (one barrier pair per 128 kv), each subtile runs the proven
// R12 inner body so only s[4] is live (no spill: VGPR 68, WRITE_SIZE 8KB).
// Prefetch in NAMED uint4 scalars. 256 threads = 4 waves x 16 q-rows.
// Grid 1024, balanced mapping (stride-256 classes sum to 66 128-steps).
// V PRE-TRANSPOSED [h][d][s] as two [64][64] subtiles. K rows at kperm'd
// positions -> zero-shuffle PV. Scalar m/l, 2-shfl reductions, T13 defer-max,
// T5 setprio, T14 register prefetch.
__global__ __launch_bounds__(256) void attn_kernel(const bf16* __restrict__ Q,
                                                   const bf16* __restrict__ Kg,
                                                   const bf16* __restrict__ Vtg,
                                                   bf16* __restrict__ O) {
    __shared__ bf16 Ks[2][64 * 64];   // [kv-subtile][swizzled kperm'd rows]
    __shared__ bf16 Vt[2][64 * 64];   // [kv-subtile][swizzled [d][kv64]]

    const int b = blockIdx.x;
    const int t = threadIdx.x;
    const int lane = t & 63;
    const int l15 = lane & 15, lhi = lane >> 4;
    const int wave = t >> 6;

    // K staging: 128 rows x 2 threads/row, 4 x 16B slots each
    const int srowK = t >> 1, halfK = t & 1;
    const int subK = srowK >> 6;
    const int kposK = kperm(srowK & 63);
    // V staging: 64 d-rows x 4 threads/row, 4 x 16B slots (qv pair -> subtile)
    const int srowV = t >> 2, qv = t & 3;
    const int vsub = qv >> 1, vcol = (qv & 1) * 4;

    // balanced unit mapping: stride-256 classes sum to 66 128-steps
    const int g = b >> 8, idx = b & 255;
    const int j = idx >> 4, h = idx & 15;
    const int qt = (g == 0) ? (63 - j) : (g == 1) ? (32 + j)
                 : (g == 2) ? (31 - j) : j;

    const bf16* qh = Q + (size_t)h * S_LEN * DK;
    const bf16* kh = Kg + (size_t)h * S_LEN * DK;
    const bf16* vh = Vtg + (size_t)h * DK * S_LEN;  // [d][s]

    const int q0w = qt * 64 + wave * 16;

    // Q B-fragments: row=q0w+l15, k chunks (scale+log2e folded in Q)
    bf16x8 qf0 = *(const bf16x8*)&qh[(size_t)(q0w + l15) * DK + lhi * 8];
    bf16x8 qf1 = *(const bf16x8*)&qh[(size_t)(q0w + l15) * DK + 32 + lhi * 8];

    float m_s = -3.0e38f, l_s = 0.f;  // scalar state for q = q0w + l15
    f32x4 oacc[4];
#pragma unroll
    for (int d = 0; d < 4; ++d) oacc[d] = (f32x4){0.f, 0.f, 0.f, 0.f};

    const int NT2 = (qt + 2) >> 1;  // ceil((qt+1)/2) 128-wide staging steps
    uint4 kr0, kr1, kr2, kr3, vr0, vr1, vr2, vr3;

    auto load_regs = [&](int kt) {
        const int k0 = kt * 128;
        const bf16* kp = &kh[(size_t)(k0 + srowK) * DK + halfK * 32];
        kr0 = *(const uint4*)(kp);
        kr1 = *(const uint4*)(kp + 8);
        kr2 = *(const uint4*)(kp + 16);
        kr3 = *(const uint4*)(kp + 24);
        const bf16* vp = &vh[(size_t)srowV * S_LEN + k0 + qv * 32];
        vr0 = *(const uint4*)(vp);
        vr1 = *(const uint4*)(vp + 8);
        vr2 = *(const uint4*)(vp + 16);
        vr3 = *(const uint4*)(vp + 24);
    };
    auto write_lds = [&]() {
        *(uint4*)&Ks[subK][swz8(kposK, halfK * 4 + 0)] = kr0;
        *(uint4*)&Ks[subK][swz8(kposK, halfK * 4 + 1)] = kr1;
        *(uint4*)&Ks[subK][swz8(kposK, halfK * 4 + 2)] = kr2;
        *(uint4*)&Ks[subK][swz8(kposK, halfK * 4 + 3)] = kr3;
        *(uint4*)&Vt[vsub][swz8(srowV, vcol + 0)] = vr0;
        *(uint4*)&Vt[vsub][swz8(srowV, vcol + 1)] = vr1;
        *(uint4*)&Vt[vsub][swz8(srowV, vcol + 2)] = vr2;
        *(uint4*)&Vt[vsub][swz8(srowV, vcol + 3)] = vr3;
    };

    load_regs(0);
    write_lds();
    __syncthreads();

    for (int kt = 0; kt < NT2; ++kt) {
        if (kt + 1 < NT2) load_regs(kt + 1);

#pragma unroll
        for (int sub = 0; sub < 2; ++sub) {
            const int k0 = kt * 128 + sub * 64;
            if (k0 <= q0w + 15) {  // causal skip for this wave's rows
                // ---- swapped QK^T over permuted K positions (R12 body):
                // s[nt][r] = P[q=q0w+l15][kv = k0+(nt>>1)*32+lhi*8+(nt&1)*4+r]
                f32x4 s[4];
                __builtin_amdgcn_s_setprio(1);
#pragma unroll
                for (int nt = 0; nt < 4; ++nt) {
                    bf16x8 kf0 = *(const bf16x8*)&Ks[sub][swz8(nt * 16 + l15, lhi)];
                    bf16x8 kf1 =
                        *(const bf16x8*)&Ks[sub][swz8(nt * 16 + l15, 4 + lhi)];
                    f32x4 c = (f32x4){0.f, 0.f, 0.f, 0.f};
                    c = mfma16(kf0, qf0, c);
                    c = mfma16(kf1, qf1, c);
                    s[nt] = c;
                }
                __builtin_amdgcn_s_setprio(0);

                // ---- causal mask (permuted kv indexing) ----
                if (k0 + 63 > q0w) {
                    const int qg = q0w + l15;
#pragma unroll
                    for (int nt = 0; nt < 4; ++nt)
#pragma unroll
                        for (int r = 0; r < 4; ++r) {
                            int kg = k0 + (nt >> 1) * 32 + lhi * 8 +
                                     (nt & 1) * 4 + r;
                            if (kg > qg) s[nt][r] = -3.0e38f;
                        }
                }

                // ---- row max: 15 fmax + 2 shfl ----
                float tm = s[0][0];
#pragma unroll
                for (int nt = 0; nt < 4; ++nt)
#pragma unroll
                    for (int r = 0; r < 4; ++r) tm = fmaxf(tm, s[nt][r]);
                tm = fmaxf(tm, __shfl_xor(tm, 16));
                tm = fmaxf(tm, __shfl_xor(tm, 32));

                // ---- defer-max (T13) ----
                if (__any(tm - m_s > 8.0f)) {
                    float mn = fmaxf(m_s, tm);
                    float alpha = exp2f(m_s - mn);
                    m_s = mn;
                    l_s *= alpha;
                    float aR[4];
#pragma unroll
                    for (int r = 0; r < 4; ++r)
                        aR[r] = __shfl(alpha, (lane & 48) | (lhi * 4 + r));
#pragma unroll
                    for (int dt = 0; dt < 4; ++dt)
#pragma unroll
                        for (int r = 0; r < 4; ++r) oacc[dt][r] *= aR[r];
                }

                // ---- P = exp2(s - m), row sum ----
                float rs = 0.f;
#pragma unroll
                for (int nt = 0; nt < 4; ++nt)
#pragma unroll
                    for (int r = 0; r < 4; ++r) {
                        float pv = exp2f(s[nt][r] - m_s);  // log2e folded in Q
                        s[nt][r] = pv;
                        rs += pv;
                    }
                rs += __shfl_xor(rs, 16);
                rs += __shfl_xor(rs, 32);
                l_s += rs;

                // ---- PV: A-frag lane-local -> pack and mfma ----
#pragma unroll
                for (int kc = 0; kc < 2; ++kc) {
                    union { unsigned int u[4]; bf16x8 v; } pf;
                    pf.u[0] = pkbf(s[2 * kc][0], s[2 * kc][1]);
                    pf.u[1] = pkbf(s[2 * kc][2], s[2 * kc][3]);
                    pf.u[2] = pkbf(s[2 * kc + 1][0], s[2 * kc + 1][1]);
                    pf.u[3] = pkbf(s[2 * kc + 1][2], s[2 * kc + 1][3]);
                    __builtin_amdgcn_s_setprio(1);
#pragma unroll
                    for (int dt = 0; dt < 4; ++dt) {
                        bf16x8 vf = *(const bf16x8*)
                            &Vt[sub][swz8(dt * 16 + l15, kc * 4 + lhi)];
                        oacc[dt] = mfma16(pf.v, vf, oacc[dt]);
                    }
                    __builtin_amdgcn_s_setprio(0);
                }
            }
        }

        __syncthreads();  // all LDS reads of this 128-tile done
        if (kt + 1 < NT2) {
            write_lds();
            __syncthreads();  // writes visible before next compute
        }
    }

    // ---- output: redistribute l to accumulator rows, store ----
    float lR[4];
#pragma unroll
    for (int r = 0; r < 4; ++r)
        lR[r] = __shfl(l_s, (lane & 48) | (lhi * 4 + r));
#pragma unroll
    for (int dt = 0; dt < 4; ++dt)
#pragma unroll
        for (int r = 0; r < 4; ++r) {
            int qg = q0w + lhi * 4 + r;
            int dg = dt * 16 + l15;
            float val = oacc[dt][r] / lR[r];
            O[(size_t)qg * DMODEL + h * DK + dg] = __float2bfloat16(val);
        }
}

extern "C" void kernel_launch(void* const* d_in, const int* in_sizes, int n_in,
                              void* d_out, int out_size, void* d_ws, size_t ws_size,
                              hipStream_t stream) {
    const float* x  = (const float*)d_in[0];
    const float* Wq = (const float*)d_in[1];
    const float* Wk = (const float*)d_in[2];
    const float* Wv = (const float*)d_in[3];
    const float* Wo = (const float*)d_in[4];
    float* out = (float*)d_out;

    bf16* q_ws = (bf16*)d_ws;                    // [H][S][64] bf16
    bf16* k_ws = q_ws + (size_t)S_LEN * DMODEL;  // [H][S][64] bf16
    bf16* v_ws = k_ws + (size_t)S_LEN * DMODEL;  // [H][64][S] bf16 (V^T)
    bf16* a_ws = v_ws + (size_t)S_LEN * DMODEL;  // [S][D] bf16

    dim3 gq(256, 1, 3);
    qkv_proj<<<gq, 256, 0, stream>>>(x, Wq, Wk, Wv, q_ws, k_ws, v_ws);
    attn_kernel<<<1024, 256, 0, stream>>>(q_ws, k_ws, v_ws, a_ws);
    out_proj<<<256, 256, 0, stream>>>(a_ws, Wo, out);
}